// Round 3
// baseline (1411.869 us; speedup 1.0000x reference)
//
#include <hip/hip_runtime.h>
#include <cstdint>
#include <cstddef>

// Problem constants (from reference)
#define OUT_F 4096
#define IN_F  11008
#define VECD  8
#define NVEC  (OUT_F * IN_F / VECD)   // 5,636,096 vectors
#define VPR   (IN_F / VECD)           // 1376 vectors per output row
#define M_DIM 4096                    // 2*2048 flattened batch*seq
#define N_DIM OUT_F
#define K_DIM IN_F

typedef __attribute__((ext_vector_type(4))) float f32x4;
typedef __attribute__((ext_vector_type(8))) __bf16 bf16x8;
typedef __attribute__((ext_vector_type(4))) unsigned int u32x4;

__device__ inline unsigned short f2bf(float f) {     // RNE (x-side)
  union { float f; unsigned int u; } v; v.f = f;
  unsigned int u = v.u;
  unsigned int r = u + 0x7FFFu + ((u >> 16) & 1u);
  return (unsigned short)(r >> 16);
}

// Pack two fp32 into one dword of bf16 (RTZ: keep hi16). 1 VALU op.
__device__ inline unsigned pk2(float hi, float lo) {
  return __builtin_amdgcn_perm(__float_as_uint(hi), __float_as_uint(lo),
                               0x07060302u);
}

// 8 fp32 -> 8 bf16 (RTZ) with scale. Bias centered by folding (1+2^-9) into s.
__device__ inline u32x4 packsc(f32x4 a, f32x4 b, float s) {
  u32x4 w;
  w.x = pk2(a.y * s, a.x * s);
  w.y = pk2(a.w * s, a.z * s);
  w.z = pk2(b.y * s, b.x * s);
  w.w = pk2(b.w * s, b.z * s);
  return w;
}

// ---------------------------------------------------------------------------
// Phase 1: cast X -> bf16 only (W dequant is fused into the GEMM now).
// Round-1 coalesced layout: 8 floats/thread, 32B/lane reads, 16B/lane writes.
// RNE rounding (VALU is free here; kernel is HBM-bound).
// ---------------------------------------------------------------------------
__global__ __launch_bounds__(256) void xcast_kernel(
    const float* __restrict__ x, unsigned short* __restrict__ xb) {
  const size_t base = (size_t)(blockIdx.x * 256 + threadIdx.x) * 8;
  const f32x4* xp = (const f32x4*)(x + base);
  f32x4 x0 = xp[0], x1 = xp[1];
  u32x4 q;
  q.x = (unsigned)f2bf(x0.x) | ((unsigned)f2bf(x0.y) << 16);
  q.y = (unsigned)f2bf(x0.z) | ((unsigned)f2bf(x0.w) << 16);
  q.z = (unsigned)f2bf(x1.x) | ((unsigned)f2bf(x1.y) << 16);
  q.w = (unsigned)f2bf(x1.z) | ((unsigned)f2bf(x1.w) << 16);
  *(u32x4*)(xb + base) = q;
}

// ---------------------------------------------------------------------------
// Phase 2: fused dequant-GEMM.  C[M,N] = Xb[M,K] * W[N,K]^T, where W rows are
// gathered from the 1 MB L2-resident codebook per K-tile (no wb in HBM).
//
// Structure = round-2 kernel (128x128 tile, 4 waves, 4x4 16x16x32 bf16 MFMA,
// XOR-swizzled LDS, zero bank conflicts) with B-staging replaced:
//   thread t -> row r=t>>1, half h=t&1: int2 index load + 2x32B codebook
//   gathers + perm-pack -> 2x ds_write_b128 into swizzled Bs slots.
// Gather for iter i+1 is issued AFTER barrier2 of iter i (inside the MFMA
// phase) so barrier1's vmcnt(0) drain sees loads that are a full MFMA phase
// old. Packed words (8 VGPRs) + next int2 are the only live-across state.
// ---------------------------------------------------------------------------
#define GLD16(g, l)                                                     \
  __builtin_amdgcn_global_load_lds(                                     \
      (const __attribute__((address_space(1))) void*)(g),               \
      (__attribute__((address_space(3))) void*)(l), 16, 0, 0)

__global__ __launch_bounds__(256) void gemm_fused_kernel(
    const unsigned short* __restrict__ A,   // M x K bf16 (cast X)
    const int* __restrict__ idxs,           // OUT_F x VPR
    const float* __restrict__ cb,           // 32768 x 8 fp32 (L2-resident)
    const float* __restrict__ scales,       // OUT_F
    float* __restrict__ C) {                // M x N fp32
  __shared__ unsigned short As[128 * 32];   // 8 KB
  __shared__ unsigned short Bs[128 * 32];   // 8 KB

  const int tid  = threadIdx.x;
  const int bm   = blockIdx.x >> 5;         // 0..31
  const int bn   = blockIdx.x & 31;         // 0..31
  const int lane = tid & 63;
  const int wave = tid >> 6;
  const int wm   = (wave & 1) * 64;
  const int wn   = (wave >> 1) * 64;
  const int lrow = lane & 15;
  const int kgrp = lane >> 4;

  // ---- A staging (unchanged from round 2; swizzled chunk choice) ----
  const int srow = tid >> 2;                // 0..63
  const int cg   = (tid & 3) ^ ((srow >> 1) & 3);
  const unsigned short* a0 = A + (size_t)(bm * 128 + srow) * K_DIM + cg * 8;
  const unsigned short* a1 = a0 + (size_t)64 * K_DIM;
  unsigned short* lA0 = &As[tid * 8];
  unsigned short* lA1 = &As[2048 + tid * 8];

  // ---- B staging: codebook gather ----
  const int r = tid >> 1;                   // 0..127 (n-row within tile)
  const int h = tid & 1;                    // which 2 of the 4 vectors
  const float sc = scales[bn * 128 + r] * 1.001953125f;  // RTZ compensation
  const int* ip = idxs + (size_t)(bn * 128 + r) * VPR + h * 2;
  const int bx = (r >> 1) & 3;              // XOR swizzle term for this row
  unsigned short* bs0 = &Bs[r * 32 + (((2 * h)     ^ bx) * 8)];
  unsigned short* bs1 = &Bs[r * 32 + (((2 * h + 1) ^ bx) * 8)];

  const int kslot = (kgrp ^ ((lrow >> 1) & 3)) * 8;

  f32x4 acc[4][4];
#pragma unroll
  for (int i = 0; i < 4; i++)
#pragma unroll
    for (int j = 0; j < 4; j++) acc[i][j] = f32x4{0.f, 0.f, 0.f, 0.f};

  // Prologue: gather+pack iter 0, prefetch indices for iter 1.
  int2 id = *(const int2*)ip;  ip += 4;
  u32x4 w0, w1;
  {
    const f32x4* g0 = (const f32x4*)(cb + (size_t)id.x * 8);
    const f32x4* g1 = (const f32x4*)(cb + (size_t)id.y * 8);
    f32x4 p0 = g0[0], p1 = g0[1], p2 = g1[0], p3 = g1[1];
    w0 = packsc(p0, p1, sc);
    w1 = packsc(p2, p3, sc);
  }
  id = *(const int2*)ip;  ip += 4;

  for (int k0 = 0; k0 < K_DIM; k0 += 32) {
    __syncthreads();                        // LDS free (all ds_reads drained)
    GLD16(a0, lA0); GLD16(a1, lA1);
    a0 += 32; a1 += 32;
    *(u32x4*)bs0 = w0;                      // ds_write_b128 x2 (balanced banks)
    *(u32x4*)bs1 = w1;
    __syncthreads();                        // vmcnt(0)+lgkmcnt(0) then barrier

    bf16x8 af[4], bfr[4];
#pragma unroll
    for (int i = 0; i < 4; i++)
      af[i] = *(const bf16x8*)&As[(wm + i * 16 + lrow) * 32 + kslot];
#pragma unroll
    for (int j = 0; j < 4; j++)
      bfr[j] = *(const bf16x8*)&Bs[(wn + j * 16 + lrow) * 32 + kslot];

    // Prefetch next B-tile (loads issued here overlap the MFMA phase; they
    // are drained by the NEXT iteration's first barrier).
    if (k0 + 32 < K_DIM) {
      const f32x4* g0 = (const f32x4*)(cb + (size_t)id.x * 8);
      const f32x4* g1 = (const f32x4*)(cb + (size_t)id.y * 8);
      f32x4 p0 = g0[0], p1 = g0[1], p2 = g1[0], p3 = g1[1];
      if (k0 + 64 < K_DIM) { id = *(const int2*)ip;  ip += 4; }
      w0 = packsc(p0, p1, sc);
      w1 = packsc(p2, p3, sc);
    }

#pragma unroll
    for (int i = 0; i < 4; i++)
#pragma unroll
      for (int j = 0; j < 4; j++)
        acc[i][j] = __builtin_amdgcn_mfma_f32_16x16x32_bf16(
            af[i], bfr[j], acc[i][j], 0, 0, 0);
  }

  // Epilogue: C/D layout col = lane&15, row = (lane>>4)*4 + reg  [m89-verified]
#pragma unroll
  for (int i = 0; i < 4; i++) {
    const int row0 = bm * 128 + wm + i * 16 + kgrp * 4;
#pragma unroll
    for (int j = 0; j < 4; j++) {
      const int col = bn * 128 + wn + j * 16 + lrow;
#pragma unroll
      for (int r2 = 0; r2 < 4; r2++)
        C[(size_t)(row0 + r2) * N_DIM + col] = acc[i][j][r2];
    }
  }
}

// ---------------------------------------------------------------------------
// Fallback (only if workspace is too small for the bf16 X): naive fp32.
// ---------------------------------------------------------------------------
__global__ __launch_bounds__(256) void naive_kernel(
    const float* __restrict__ x, const int* __restrict__ indices,
    const float* __restrict__ cb, const float* __restrict__ scales,
    float* __restrict__ out) {
  int n = blockIdx.x * 256 + threadIdx.x;
  int m = blockIdx.y;
  if (n >= N_DIM) return;
  float s = scales[n];
  const float* xr = x + (size_t)m * IN_F;
  const int* ir = indices + (size_t)n * VPR;
  float acc = 0.f;
  for (int v = 0; v < VPR; v++) {
    int id = ir[v];
    const float* c = cb + (size_t)id * 8;
#pragma unroll
    for (int e = 0; e < 8; e++) acc += xr[v * 8 + e] * c[e];
  }
  out[(size_t)m * N_DIM + n] = acc * s;
}

extern "C" void kernel_launch(void* const* d_in, const int* in_sizes, int n_in,
                              void* d_out, int out_size, void* d_ws, size_t ws_size,
                              hipStream_t stream) {
  const float* x       = (const float*)d_in[0];   // (2,2048,11008) fp32
  const int*   indices = (const int*)d_in[1];     // (5636096,) int32
  const float* cb      = (const float*)d_in[2];   // (32768,8) fp32
  const float* scales  = (const float*)d_in[3];   // (4096,1) fp32
  float* out = (float*)d_out;                     // (2,2048,4096) fp32

  const size_t xb_elems = (size_t)M_DIM * K_DIM;  // 45,088,768
  const size_t need = xb_elems * sizeof(unsigned short);  // ~90 MB

  if (ws_size >= need) {
    unsigned short* xb = (unsigned short*)d_ws;
    xcast_kernel<<<(int)(xb_elems / 8 / 256), 256, 0, stream>>>(x, xb);
    gemm_fused_kernel<<<(M_DIM / 128) * (N_DIM / 128), 256, 0, stream>>>(
        xb, indices, cb, scales, out);
  } else {
    naive_kernel<<<dim3(N_DIM / 256, M_DIM), 256, 0, stream>>>(x, indices, cb,
                                                               scales, out);
  }
}

// Round 4
// 1062.117 us; speedup vs baseline: 1.3293x; 1.3293x over previous
//
#include <hip/hip_runtime.h>
#include <cstdint>
#include <cstddef>

// Problem constants (from reference)
#define OUT_F 4096
#define IN_F  11008
#define VECD  8
#define NVEC  (OUT_F * IN_F / VECD)   // 5,636,096 vectors
#define VPR   (IN_F / VECD)           // 1376 vectors per output row
#define M_DIM 4096                    // 2*2048 flattened batch*seq
#define N_DIM OUT_F
#define K_DIM IN_F

typedef __attribute__((ext_vector_type(4))) float f32x4;
typedef __attribute__((ext_vector_type(8))) __bf16 bf16x8;
typedef __attribute__((ext_vector_type(4))) unsigned int u32x4;
typedef __attribute__((ext_vector_type(2))) unsigned int u32x2;

__device__ inline unsigned short f2bf(float f) {     // RNE
  union { float f; unsigned int u; } v; v.f = f;
  unsigned int u = v.u;
  unsigned int r = u + 0x7FFFu + ((u >> 16) & 1u);
  return (unsigned short)(r >> 16);
}

__device__ inline u32x2 pack4(f32x4 a, float s) {
  u32x2 q;
  q.x = (unsigned)f2bf(a.x * s) | ((unsigned)f2bf(a.y * s) << 16);
  q.y = (unsigned)f2bf(a.z * s) | ((unsigned)f2bf(a.w * s) << 16);
  return q;
}

// ---------------------------------------------------------------------------
// Phase 1a: W dequant -> bf16 (wb).  Grid-stride x4: 4 INDEPENDENT
// idx->gather->pack->store chains per thread, all loads lane-dense.
// (Round 1/2 lesson: adjacent-chunk-per-thread layouts ran at 1.4-1.5 TB/s;
// lane-dense float4 is the m13-verified 6.3 TB/s pattern.)
// ---------------------------------------------------------------------------
__global__ __launch_bounds__(256) void wdequant_kernel(
    const int* __restrict__ indices, const float* __restrict__ cb,
    const float* __restrict__ scales, unsigned short* __restrict__ wb) {
  const int N = NVEC / 4;                       // threads in grid
  const int gid = blockIdx.x * 256 + threadIdx.x;
  const int v0 = gid, v1 = gid + N, v2 = gid + 2 * N, v3 = gid + 3 * N;

  // 4 independent index loads (lane-dense 4B)
  int i0 = indices[v0], i1 = indices[v1], i2 = indices[v2], i3 = indices[v3];
  // 4 independent scale loads
  float s0 = scales[v0 / VPR], s1 = scales[v1 / VPR];
  float s2 = scales[v2 / VPR], s3 = scales[v3 / VPR];
  // 8 independent gathers, all in flight
  const f32x4* g0 = (const f32x4*)(cb + (size_t)i0 * 8);
  const f32x4* g1 = (const f32x4*)(cb + (size_t)i1 * 8);
  const f32x4* g2 = (const f32x4*)(cb + (size_t)i2 * 8);
  const f32x4* g3 = (const f32x4*)(cb + (size_t)i3 * 8);
  f32x4 a0 = g0[0], b0 = g0[1], a1 = g1[0], b1 = g1[1];
  f32x4 a2 = g2[0], b2 = g2[1], a3 = g3[0], b3 = g3[1];

  // lane-dense 16B stores
  u32x4 w;
  w.xy = pack4(a0, s0); w.zw = pack4(b0, s0);
  *(u32x4*)(wb + (size_t)v0 * 8) = w;
  w.xy = pack4(a1, s1); w.zw = pack4(b1, s1);
  *(u32x4*)(wb + (size_t)v1 * 8) = w;
  w.xy = pack4(a2, s2); w.zw = pack4(b2, s2);
  *(u32x4*)(wb + (size_t)v2 * 8) = w;
  w.xy = pack4(a3, s3); w.zw = pack4(b3, s3);
  *(u32x4*)(wb + (size_t)v3 * 8) = w;
}

// ---------------------------------------------------------------------------
// Phase 1b: cast X -> bf16 (xb).  Grid-stride x4, lane-dense f32x4 reads
// (16B/lane) and uint2 writes (8B/lane).
// ---------------------------------------------------------------------------
__global__ __launch_bounds__(256) void xcast_kernel(
    const float* __restrict__ x, unsigned short* __restrict__ xb) {
  const size_t N = (size_t)M_DIM * K_DIM / 16;  // f32x4 units / 4 = threads
  const size_t gid = blockIdx.x * 256 + threadIdx.x;
  const f32x4* xp = (const f32x4*)x;
#pragma unroll
  for (int j = 0; j < 4; j++) {
    const size_t u = gid + (size_t)j * N;       // f32x4 unit index
    f32x4 a = xp[u];
    *(u32x2*)(xb + u * 4) = pack4(a, 1.f);
  }
}

// ---------------------------------------------------------------------------
// Phase 2: C[M,N] = A[M,K] * B[N,K]^T (both bf16, K-contiguous; fp32 out)
// Round-2 kernel (zero bank conflicts) + XCD-aware tile ownership:
//   xcd = blockIdx%8 (round-robin dispatch heuristic), bn = xcd*4 + (g>>5),
//   bm = g&31  ->  each bn-tile (2.8 MB B rows) is consumed by exactly ONE
//   XCD; its 32 bm-sharers progress in a shared k-window, so the hot B slice
//   stays in that XCD's 4 MB L2. B is fetched once chip-wide (90 MB instead
//   of 8x), feed shifts from L3 (~10 TB/s, round-2 limiter) to L2.
// ---------------------------------------------------------------------------
#define GLD16(g, l)                                                     \
  __builtin_amdgcn_global_load_lds(                                     \
      (const __attribute__((address_space(1))) void*)(g),               \
      (__attribute__((address_space(3))) void*)(l), 16, 0, 0)

__global__ __launch_bounds__(256) void gemm_bt_kernel(
    const unsigned short* __restrict__ A,   // M x K bf16 (X)
    const unsigned short* __restrict__ B,   // N x K bf16 (W)
    float* __restrict__ C) {                // M x N fp32
  __shared__ unsigned short As[128 * 32];   // 8 KB
  __shared__ unsigned short Bs[128 * 32];   // 8 KB

  const int tid  = threadIdx.x;
  const int xcd  = blockIdx.x & 7;
  const int g    = blockIdx.x >> 3;
  const int bm   = g & 31;
  const int bn   = xcd * 4 + (g >> 5);
  const int lane = tid & 63;
  const int wave = tid >> 6;
  const int wm   = (wave & 1) * 64;
  const int wn   = (wave >> 1) * 64;
  const int lrow = lane & 15;
  const int kgrp = lane >> 4;

  // Staging: thread t owns LDS slot (row=t>>2 [+64], cs=t&3) at &LDS[t*8].
  // It fetches global chunk cg = cs ^ ((row>>1)&3)  (XOR bank swizzle).
  const int srow = tid >> 2;
  const int cg   = (tid & 3) ^ ((srow >> 1) & 3);
  const int scol = cg * 8;
  const unsigned short* a0 = A + (size_t)(bm * 128 + srow) * K_DIM + scol;
  const unsigned short* a1 = a0 + (size_t)64 * K_DIM;
  const unsigned short* b0 = B + (size_t)(bn * 128 + srow) * K_DIM + scol;
  const unsigned short* b1 = b0 + (size_t)64 * K_DIM;
  unsigned short* lA0 = &As[tid * 8];
  unsigned short* lA1 = &As[2048 + tid * 8];
  unsigned short* lB0 = &Bs[tid * 8];
  unsigned short* lB1 = &Bs[2048 + tid * 8];

  // Reader-side swizzled k-slot (constant per lane across all i/j).
  const int kslot = (kgrp ^ ((lrow >> 1) & 3)) * 8;

  f32x4 acc[4][4];
#pragma unroll
  for (int i = 0; i < 4; i++)
#pragma unroll
    for (int j = 0; j < 4; j++) acc[i][j] = f32x4{0.f, 0.f, 0.f, 0.f};

  for (int k0 = 0; k0 < K_DIM; k0 += 32) {
    __syncthreads();                        // protect LDS from overwrite
    GLD16(a0, lA0); GLD16(a1, lA1);
    GLD16(b0, lB0); GLD16(b1, lB1);
    a0 += 32; a1 += 32; b0 += 32; b1 += 32;
    __syncthreads();                        // drains vmcnt(0) then s_barrier

    bf16x8 af[4], bfr[4];
#pragma unroll
    for (int i = 0; i < 4; i++)
      af[i] = *(const bf16x8*)&As[(wm + i * 16 + lrow) * 32 + kslot];
#pragma unroll
    for (int j = 0; j < 4; j++)
      bfr[j] = *(const bf16x8*)&Bs[(wn + j * 16 + lrow) * 32 + kslot];

#pragma unroll
    for (int i = 0; i < 4; i++)
#pragma unroll
      for (int j = 0; j < 4; j++)
        acc[i][j] = __builtin_amdgcn_mfma_f32_16x16x32_bf16(
            af[i], bfr[j], acc[i][j], 0, 0, 0);
  }

  // Epilogue: C/D layout col = lane&15, row = (lane>>4)*4 + reg  [m89-verified]
#pragma unroll
  for (int i = 0; i < 4; i++) {
    const int row0 = bm * 128 + wm + i * 16 + kgrp * 4;
#pragma unroll
    for (int j = 0; j < 4; j++) {
      const int col = bn * 128 + wn + j * 16 + lrow;
#pragma unroll
      for (int r = 0; r < 4; r++)
        C[(size_t)(row0 + r) * N_DIM + col] = acc[i][j][r];
    }
  }
}

// ---------------------------------------------------------------------------
// Fallback (only if workspace is too small for the bf16 operands).
// ---------------------------------------------------------------------------
__global__ __launch_bounds__(256) void naive_kernel(
    const float* __restrict__ x, const int* __restrict__ indices,
    const float* __restrict__ cb, const float* __restrict__ scales,
    float* __restrict__ out) {
  int n = blockIdx.x * 256 + threadIdx.x;
  int m = blockIdx.y;
  if (n >= N_DIM) return;
  float s = scales[n];
  const float* xr = x + (size_t)m * IN_F;
  const int* ir = indices + (size_t)n * VPR;
  float acc = 0.f;
  for (int v = 0; v < VPR; v++) {
    int id = ir[v];
    const float* c = cb + (size_t)id * 8;
#pragma unroll
    for (int e = 0; e < 8; e++) acc += xr[v * 8 + e] * c[e];
  }
  out[(size_t)m * N_DIM + n] = acc * s;
}

extern "C" void kernel_launch(void* const* d_in, const int* in_sizes, int n_in,
                              void* d_out, int out_size, void* d_ws, size_t ws_size,
                              hipStream_t stream) {
  const float* x       = (const float*)d_in[0];   // (2,2048,11008) fp32
  const int*   indices = (const int*)d_in[1];     // (5636096,) int32
  const float* cb      = (const float*)d_in[2];   // (32768,8) fp32
  const float* scales  = (const float*)d_in[3];   // (4096,1) fp32
  float* out = (float*)d_out;                     // (2,2048,4096) fp32

  const size_t xb_elems = (size_t)M_DIM * K_DIM;  // 45,088,768
  const size_t wb_elems = (size_t)N_DIM * K_DIM;  // 45,088,768
  const size_t need = (xb_elems + wb_elems) * sizeof(unsigned short); // ~172 MB

  if (ws_size >= need) {
    unsigned short* xb = (unsigned short*)d_ws;
    unsigned short* wb = xb + xb_elems;
    wdequant_kernel<<<NVEC / 4 / 256, 256, 0, stream>>>(indices, cb, scales,
                                                        wb);
    xcast_kernel<<<(int)(xb_elems / 16 / 256), 256, 0, stream>>>(x, xb);
    gemm_bt_kernel<<<(M_DIM / 128) * (N_DIM / 128), 256, 0, stream>>>(xb, wb,
                                                                      out);
  } else {
    naive_kernel<<<dim3(N_DIM / 256, M_DIM), 256, 0, stream>>>(x, indices, cb,
                                                               scales, out);
  }
}

// Round 5
// 635.498 us; speedup vs baseline: 2.2217x; 1.6713x over previous
//
#include <hip/hip_runtime.h>
#include <cstdint>
#include <cstddef>

// Problem constants (from reference)
#define OUT_F 4096
#define IN_F  11008
#define VECD  8
#define NVEC  (OUT_F * IN_F / VECD)   // 5,636,096 vectors
#define VPR   (IN_F / VECD)           // 1376 vectors per output row
#define M_DIM 4096                    // 2*2048 flattened batch*seq
#define N_DIM OUT_F
#define K_DIM IN_F

typedef __attribute__((ext_vector_type(4))) float f32x4;
typedef __attribute__((ext_vector_type(8))) __bf16 bf16x8;
typedef __attribute__((ext_vector_type(4))) unsigned int u32x4;

__device__ inline unsigned short f2bf(float f) {     // RNE
  union { float f; unsigned int u; } v; v.f = f;
  unsigned int u = v.u;
  unsigned int r = u + 0x7FFFu + ((u >> 16) & 1u);
  return (unsigned short)(r >> 16);
}

// ---------------------------------------------------------------------------
// Phase 1: dequant W + cast X -> bf16.  EXACT round-1 kernel: measured best
// (~258 µs); rounds 2/4 restructurings were neutral-to-worse, so phase-1 is
// not coalescing-bound — stop fiddling.
// ---------------------------------------------------------------------------
__global__ __launch_bounds__(256) void dequant_cast_kernel(
    const float* __restrict__ x, const int* __restrict__ indices,
    const float* __restrict__ cb, const float* __restrict__ scales,
    unsigned short* __restrict__ xb, unsigned short* __restrict__ wb) {
  int v = blockIdx.x * 256 + threadIdx.x;
  if (v >= NVEC) return;

  int id = indices[v];
  int o  = v / VPR;
  float s = scales[o];

  const f32x4* c = (const f32x4*)(cb + (size_t)id * VECD);
  f32x4 c0 = c[0], c1 = c[1];
  u32x4 w;
  w.x = (unsigned)f2bf(c0.x * s) | ((unsigned)f2bf(c0.y * s) << 16);
  w.y = (unsigned)f2bf(c0.z * s) | ((unsigned)f2bf(c0.w * s) << 16);
  w.z = (unsigned)f2bf(c1.x * s) | ((unsigned)f2bf(c1.y * s) << 16);
  w.w = (unsigned)f2bf(c1.z * s) | ((unsigned)f2bf(c1.w * s) << 16);
  *(u32x4*)(wb + (size_t)v * 8) = w;

  const f32x4* xp = (const f32x4*)(x + (size_t)v * 8);
  f32x4 x0 = xp[0], x1 = xp[1];
  u32x4 q;
  q.x = (unsigned)f2bf(x0.x) | ((unsigned)f2bf(x0.y) << 16);
  q.y = (unsigned)f2bf(x0.z) | ((unsigned)f2bf(x0.w) << 16);
  q.z = (unsigned)f2bf(x1.x) | ((unsigned)f2bf(x1.y) << 16);
  q.w = (unsigned)f2bf(x1.z) | ((unsigned)f2bf(x1.w) << 16);
  *(u32x4*)(xb + (size_t)v * 8) = q;
}

// ---------------------------------------------------------------------------
// Phase 2: C[M,N] = A[M,K] * B[N,K]^T (bf16, K-contiguous; fp32 out)
//
// 256x256 tile, 512 threads (8 waves, wave-tile 128x64, acc[8][4]).
// Feed halves vs 128^2 (2.88 GB vs 5.6 GB — round-2 was feed-bound at
// 10.2 TB/s). Grid = 256 blocks = 1/CU (96 KB LDS enforces it), so NO
// implicit cross-block latency hiding -> depth-2 software pipeline:
// 3 LDS buffers, raw `s_waitcnt vmcnt(4); s_barrier` per iter (keeps the
// 4 newest global_load_lds in flight across the barrier, AITER-style).
// Safety: buffer (k+2)%3 was last read at iter k-1, whose ds_reads complete
// before barrier k; tail iters issue clamped redundant fetches so the
// outstanding-load count stays uniform (vmcnt(4) always correct).
// XOR bank swizzle from round 2 retained (zero conflicts, verified).
// ---------------------------------------------------------------------------
#define GLD16(g, l)                                                     \
  __builtin_amdgcn_global_load_lds(                                     \
      (const __attribute__((address_space(1))) void*)(g),               \
      (__attribute__((address_space(3))) void*)(l), 16, 0, 0)

__global__ __launch_bounds__(512, 2) void gemm_bt_kernel(
    const unsigned short* __restrict__ A,   // M x K bf16 (X)
    const unsigned short* __restrict__ B,   // N x K bf16 (W)
    float* __restrict__ C) {                // M x N fp32
  extern __shared__ unsigned short SMEM[];  // 3*(8192+8192) = 96 KB
  unsigned short* SA = SMEM;                // [3][8192]
  unsigned short* SB = SMEM + 3 * 8192;     // [3][8192]

  const int tid  = threadIdx.x;
  const int bm   = blockIdx.x >> 4;         // 0..15
  const int bn   = blockIdx.x & 15;         // 0..15
  const int lane = tid & 63;
  const int wave = tid >> 6;                // 0..7
  const int wm   = (wave & 1) * 128;        // 2 waves in M
  const int wn   = (wave >> 1) * 64;        // 4 waves in N
  const int lrow = lane & 15;
  const int kgrp = lane >> 4;
  const int kslot = (kgrp ^ ((lrow >> 1) & 3)) * 8;

  // Staging: 512 threads, 4 GLD16 each = 32 KB/iter. Thread t owns LDS slot
  // (row = t>>2 [+128], chunk cs = t&3); fetches global chunk cs^((row>>1)&3)
  // (same XOR term for row+128 since 128/2 ≡ 0 mod 4).
  const int srow = tid >> 2;                // 0..127
  const int cg   = (tid & 3) ^ ((srow >> 1) & 3);
  const unsigned short* a0 = A + (size_t)(bm * 256 + srow) * K_DIM + cg * 8;
  const unsigned short* a1 = a0 + (size_t)128 * K_DIM;
  const unsigned short* b0 = B + (size_t)(bn * 256 + srow) * K_DIM + cg * 8;
  const unsigned short* b1 = b0 + (size_t)128 * K_DIM;
  const int l0 = tid * 8;                   // rows 0..127 region
  const int l1 = 4096 + tid * 8;            // rows 128..255 region

#define STAGE(pbuf, kf)                                   \
  do {                                                    \
    GLD16(a0 + (kf), &SA[(pbuf) * 8192 + l0]);            \
    GLD16(a1 + (kf), &SA[(pbuf) * 8192 + l1]);            \
    GLD16(b0 + (kf), &SB[(pbuf) * 8192 + l0]);            \
    GLD16(b1 + (kf), &SB[(pbuf) * 8192 + l1]);            \
  } while (0)

  f32x4 acc[8][4];
#pragma unroll
  for (int i = 0; i < 8; i++)
#pragma unroll
    for (int j = 0; j < 4; j++) acc[i][j] = f32x4{0.f, 0.f, 0.f, 0.f};

  STAGE(0, 0);                              // tile 0 -> buf 0
  STAGE(1, 32);                             // tile 1 -> buf 1
  int cbuf = 0, pbuf = 2;

  for (int k0 = 0; k0 < K_DIM; k0 += 32) {
    // Wait for the OLDEST 4 loads (this iter's tile); keep newest 4 flying.
    asm volatile("s_waitcnt vmcnt(4)\n\ts_barrier" ::: "memory");

    int kf = k0 + 64;                       // prefetch tile k+2 (clamped tail)
    if (kf > K_DIM - 32) kf = K_DIM - 32;
    STAGE(pbuf, kf);

    bf16x8 af[8], bfr[4];
#pragma unroll
    for (int i = 0; i < 8; i++)
      af[i] = *(const bf16x8*)&SA[cbuf * 8192 + (wm + i * 16 + lrow) * 32 + kslot];
#pragma unroll
    for (int j = 0; j < 4; j++)
      bfr[j] = *(const bf16x8*)&SB[cbuf * 8192 + (wn + j * 16 + lrow) * 32 + kslot];

#pragma unroll
    for (int i = 0; i < 8; i++)
#pragma unroll
      for (int j = 0; j < 4; j++)
        acc[i][j] = __builtin_amdgcn_mfma_f32_16x16x32_bf16(
            af[i], bfr[j], acc[i][j], 0, 0, 0);

    cbuf = (cbuf == 2) ? 0 : cbuf + 1;
    pbuf = (pbuf == 2) ? 0 : pbuf + 1;
  }
#undef STAGE

  // Epilogue: C/D layout col = lane&15, row = (lane>>4)*4 + reg  [m89-verified]
#pragma unroll
  for (int i = 0; i < 8; i++) {
    const int row0 = bm * 256 + wm + i * 16 + kgrp * 4;
#pragma unroll
    for (int j = 0; j < 4; j++) {
      const int col = bn * 256 + wn + j * 16 + lrow;
#pragma unroll
      for (int r = 0; r < 4; r++)
        C[(size_t)(row0 + r) * N_DIM + col] = acc[i][j][r];
    }
  }
}

// ---------------------------------------------------------------------------
// Fallback (only if workspace is too small for the bf16 operands).
// ---------------------------------------------------------------------------
__global__ __launch_bounds__(256) void naive_kernel(
    const float* __restrict__ x, const int* __restrict__ indices,
    const float* __restrict__ cb, const float* __restrict__ scales,
    float* __restrict__ out) {
  int n = blockIdx.x * 256 + threadIdx.x;
  int m = blockIdx.y;
  if (n >= N_DIM) return;
  float s = scales[n];
  const float* xr = x + (size_t)m * IN_F;
  const int* ir = indices + (size_t)n * VPR;
  float acc = 0.f;
  for (int v = 0; v < VPR; v++) {
    int id = ir[v];
    const float* c = cb + (size_t)id * 8;
#pragma unroll
    for (int e = 0; e < 8; e++) acc += xr[v * 8 + e] * c[e];
  }
  out[(size_t)m * N_DIM + n] = acc * s;
}

extern "C" void kernel_launch(void* const* d_in, const int* in_sizes, int n_in,
                              void* d_out, int out_size, void* d_ws, size_t ws_size,
                              hipStream_t stream) {
  const float* x       = (const float*)d_in[0];   // (2,2048,11008) fp32
  const int*   indices = (const int*)d_in[1];     // (5636096,) int32
  const float* cb      = (const float*)d_in[2];   // (32768,8) fp32
  const float* scales  = (const float*)d_in[3];   // (4096,1) fp32
  float* out = (float*)d_out;                     // (2,2048,4096) fp32

  const size_t xb_elems = (size_t)M_DIM * K_DIM;  // 45,088,768
  const size_t wb_elems = (size_t)N_DIM * K_DIM;  // 45,088,768
  const size_t need = (xb_elems + wb_elems) * sizeof(unsigned short); // ~172 MB

  if (ws_size >= need) {
    unsigned short* xb = (unsigned short*)d_ws;
    unsigned short* wb = xb + xb_elems;
    dequant_cast_kernel<<<NVEC / 256, 256, 0, stream>>>(x, indices, cb, scales,
                                                        xb, wb);
    gemm_bt_kernel<<<(M_DIM / 256) * (N_DIM / 256), 512, 6 * 8192 * 2, stream>>>(
        xb, wb, out);
  } else {
    naive_kernel<<<dim3(N_DIM / 256, M_DIM), 256, 0, stream>>>(x, indices, cb,
                                                               scales, out);
  }
}